// Round 11
// baseline (434.744 us; speedup 1.0000x reference)
//
#include <hip/hip_runtime.h>
#include <math.h>

// MAM dense: C[i,j] = max_k(A[i,k]*W[j,k]) + min_k(A[i,k]*W[j,k]) + bias[j]
// A = x flat [M=2048, K=768]; W [N=768, K=768] row-major; out [M,N] f32.
// fp16 packed math. R10 diagnosis: per-wave LDS dependency stalls (2 reads ->
// 96cy compute, no prefetch depth; compiler chose a 40-VGPR serial schedule).
// This round: TM8xTN4 (3 b128 reads feed 200cy of compute), explicit 1-deep
// kk2 prefetch with NAMED h8 regs, launch_bounds(256,3) for VGPR headroom.
// Split-K x4: grid 768 = 3 blocks/CU. No lambdas, no runtime-indexed arrays.

#define M_DIM 2048
#define N_DIM 768
#define K_DIM 768
#define NOUT (M_DIM * N_DIM)   // 1572864

#define BM 128
#define BN 64
#define BK 64
#define KP 32                  // k-pair rows per tile
#define SAH 132                // A row stride, h2 units (mult of 4 -> b128 ok)
#define SBH 68                 // B row stride

typedef _Float16 h2 __attribute__((ext_vector_type(2)));   // 4 B
typedef _Float16 h8 __attribute__((ext_vector_type(8)));   // 16 B = b128

static __device__ __forceinline__ h2 cvt_pk(float x, float y) {
    return __builtin_bit_cast(h2, __builtin_amdgcn_cvt_pkrtz(x, y));
}
static __device__ __forceinline__ h2 h2max(h2 a, h2 b) { return __builtin_elementwise_max(a, b); }
static __device__ __forceinline__ h2 h2min(h2 a, h2 b) { return __builtin_elementwise_min(a, b); }
static __device__ __forceinline__ unsigned packmm(h2 px, h2 pn) {
    h2 r;
    r.x = px.x >= px.y ? px.x : px.y;   // combined running max
    r.y = pn.x <= pn.y ? pn.x : pn.y;   // combined running min
    return __builtin_bit_cast(unsigned, r);
}

// LDS read helpers; k2 is compile-time under full unroll.
// Swizzle: data col c lives at LDS word c ^ (4*((kk2>>1)&7)).
#define SWZC(k2) (4 * (((k2) >> 1) & 7))
#define LDA0(k2) (*(const h8*)(As + (k2) * SAH + ((m8) ^ (SWZC(k2) & 24))))
#define LDA1(k2) (*(const h8*)(As + (k2) * SAH + ((m8) ^ (SWZC(k2) & 24)) + 4))
#define LDB_(k2) (*(const h8*)(Bs + (k2) * SBH + ((n4) ^ SWZC(k2))))

// 96 pk ops on one kk2 slice. SW_ (compile-time) selects chunk order:
// cc&4 swaps which b128 holds rows 0..3 vs 4..7.
#define MAMOPS(A0_, A1_, B_, SW_) do {                                        \
    const h8 alo_ = (SW_) ? (A1_) : (A0_);                                    \
    const h8 ahi_ = (SW_) ? (A0_) : (A1_);                                    \
    const h2 aa_[8] = {                                                       \
        __builtin_shufflevector(alo_, alo_, 0, 1),                            \
        __builtin_shufflevector(alo_, alo_, 2, 3),                            \
        __builtin_shufflevector(alo_, alo_, 4, 5),                            \
        __builtin_shufflevector(alo_, alo_, 6, 7),                            \
        __builtin_shufflevector(ahi_, ahi_, 0, 1),                            \
        __builtin_shufflevector(ahi_, ahi_, 2, 3),                            \
        __builtin_shufflevector(ahi_, ahi_, 4, 5),                            \
        __builtin_shufflevector(ahi_, ahi_, 6, 7)};                           \
    const h2 bb_[4] = {                                                       \
        __builtin_shufflevector(B_, B_, 0, 1),                                \
        __builtin_shufflevector(B_, B_, 2, 3),                                \
        __builtin_shufflevector(B_, B_, 4, 5),                                \
        __builtin_shufflevector(B_, B_, 6, 7)};                               \
    _Pragma("unroll")                                                         \
    for (int i_ = 0; i_ < 8; ++i_) {                                          \
        _Pragma("unroll")                                                     \
        for (int j_ = 0; j_ < 4; ++j_) {                                      \
            const h2 p_ = aa_[i_] * bb_[j_];                                  \
            pmax[i_][j_] = h2max(pmax[i_][j_], p_);                           \
            pmin[i_][j_] = h2min(pmin[i_][j_], p_);                           \
        }                                                                     \
    }                                                                         \
} while (0)

template <int NSPL>
__global__ __launch_bounds__(256, 3) void mam_main(
    const float* __restrict__ A, const float* __restrict__ W,
    const float* __restrict__ bias, float* __restrict__ out,
    unsigned* __restrict__ ws)
{
    __shared__ __align__(16) h2 As[KP * SAH];   // 16896 B
    __shared__ __align__(16) h2 Bs[KP * SBH];   //  8704 B (25.6 KB -> 3 blk/CU)

    const int tid = threadIdx.x;
    const int m0  = blockIdx.y * BM;
    const int n0  = blockIdx.x * BN;
    const int NT  = 12 / NSPL;                  // k-tiles per block
    const int kb  = blockIdx.z * NT * BK;

    const int mt = tid >> 4;                    // 0..15 -> rows m8..m8+7
    const int nt = tid & 15;                    // 0..15 -> cols n4..n4+3
    const int m8 = mt * 8;
    const int n4 = nt * 4;

    h2 pmax[8][4], pmin[8][4];
    const _Float16 HMIN = (_Float16)(-65504.0f), HMAX = (_Float16)(65504.0f);
#pragma unroll
    for (int i = 0; i < 8; ++i)
#pragma unroll
        for (int j = 0; j < 4; ++j) {
            pmax[i][j] = (h2){HMIN, HMIN};
            pmin[i][j] = (h2){HMAX, HMAX};
        }

    // staging map: A rows arow+16q (q=0..7), B rows arow+16q (q=0..3),
    // k-chunk akc -> kk2 rows 2akc, 2akc+1.
    const int arow = tid >> 4;                  // 0..15
    const int akc  = tid & 15;
    const int swz  = 4 * (akc & 7);             // matches read-side SWZC
    const float* Ap = A + (size_t)(m0 + arow) * K_DIM + kb + akc * 4;
    const float* Wp = W + (size_t)(n0 + arow) * K_DIM + kb + akc * 4;

    float4 ga0, ga1, ga2, ga3, ga4, ga5, ga6, ga7, gb0, gb1, gb2, gb3;

#define GLOAD(t) do {                                                         \
        const float* An_ = Ap + (t) * BK;                                     \
        const float* Wn_ = Wp + (t) * BK;                                     \
        ga0 = *(const float4*)(An_ + (size_t)  0 * K_DIM);                    \
        ga1 = *(const float4*)(An_ + (size_t) 16 * K_DIM);                    \
        ga2 = *(const float4*)(An_ + (size_t) 32 * K_DIM);                    \
        ga3 = *(const float4*)(An_ + (size_t) 48 * K_DIM);                    \
        ga4 = *(const float4*)(An_ + (size_t) 64 * K_DIM);                    \
        ga5 = *(const float4*)(An_ + (size_t) 80 * K_DIM);                    \
        ga6 = *(const float4*)(An_ + (size_t) 96 * K_DIM);                    \
        ga7 = *(const float4*)(An_ + (size_t)112 * K_DIM);                    \
        gb0 = *(const float4*)(Wn_ + (size_t)  0 * K_DIM);                    \
        gb1 = *(const float4*)(Wn_ + (size_t) 16 * K_DIM);                    \
        gb2 = *(const float4*)(Wn_ + (size_t) 32 * K_DIM);                    \
        gb3 = *(const float4*)(Wn_ + (size_t) 48 * K_DIM);                    \
    } while (0)

#define SWRITE() do {                                                         \
        h2* Aw_ = As + 2 * akc * SAH;                                         \
        h2* Bw_ = Bs + 2 * akc * SBH;                                         \
        int c_;                                                               \
        c_ = (arow +   0) ^ swz; Aw_[c_] = cvt_pk(ga0.x, ga0.y); Aw_[SAH + c_] = cvt_pk(ga0.z, ga0.w); \
        c_ = (arow +  16) ^ swz; Aw_[c_] = cvt_pk(ga1.x, ga1.y); Aw_[SAH + c_] = cvt_pk(ga1.z, ga1.w); \
        c_ = (arow +  32) ^ swz; Aw_[c_] = cvt_pk(ga2.x, ga2.y); Aw_[SAH + c_] = cvt_pk(ga2.z, ga2.w); \
        c_ = (arow +  48) ^ swz; Aw_[c_] = cvt_pk(ga3.x, ga3.y); Aw_[SAH + c_] = cvt_pk(ga3.z, ga3.w); \
        c_ = (arow +  64) ^ swz; Aw_[c_] = cvt_pk(ga4.x, ga4.y); Aw_[SAH + c_] = cvt_pk(ga4.z, ga4.w); \
        c_ = (arow +  80) ^ swz; Aw_[c_] = cvt_pk(ga5.x, ga5.y); Aw_[SAH + c_] = cvt_pk(ga5.z, ga5.w); \
        c_ = (arow +  96) ^ swz; Aw_[c_] = cvt_pk(ga6.x, ga6.y); Aw_[SAH + c_] = cvt_pk(ga6.z, ga6.w); \
        c_ = (arow + 112) ^ swz; Aw_[c_] = cvt_pk(ga7.x, ga7.y); Aw_[SAH + c_] = cvt_pk(ga7.z, ga7.w); \
        c_ = (arow +   0) ^ swz; Bw_[c_] = cvt_pk(gb0.x, gb0.y); Bw_[SBH + c_] = cvt_pk(gb0.z, gb0.w); \
        c_ = (arow +  16) ^ swz; Bw_[c_] = cvt_pk(gb1.x, gb1.y); Bw_[SBH + c_] = cvt_pk(gb1.z, gb1.w); \
        c_ = (arow +  32) ^ swz; Bw_[c_] = cvt_pk(gb2.x, gb2.y); Bw_[SBH + c_] = cvt_pk(gb2.z, gb2.w); \
        c_ = (arow +  48) ^ swz; Bw_[c_] = cvt_pk(gb3.x, gb3.y); Bw_[SBH + c_] = cvt_pk(gb3.z, gb3.w); \
    } while (0)

    // prologue
    GLOAD(0);
    SWRITE();
    __syncthreads();

#pragma unroll 1
    for (int t = 0; t < NT; ++t) {
        if (t + 1 < NT) GLOAD(t + 1);   // issue early; lands during compute

        // compute tile t: full unroll, explicit 1-deep kk2 prefetch
        {
            h8 cA0 = LDA0(0), cA1 = LDA1(0), cB = LDB_(0);
#pragma unroll
            for (int k2 = 0; k2 < KP - 1; ++k2) {
                const h8 nA0 = LDA0(k2 + 1);
                const h8 nA1 = LDA1(k2 + 1);
                const h8 nB  = LDB_(k2 + 1);
                MAMOPS(cA0, cA1, cB, ((k2) & 2) != 0);
                cA0 = nA0; cA1 = nA1; cB = nB;
            }
            MAMOPS(cA0, cA1, cB, ((KP - 1) & 2) != 0);
        }

        if (t + 1 < NT) {
            __syncthreads();            // all waves done reading
            SWRITE();                   // waits own vmcnt
            __syncthreads();
        }
    }

    if (NSPL == 1) {
        const float4 bv = *(const float4*)(bias + n0 + n4);
#pragma unroll
        for (int i = 0; i < 8; ++i) {
            float4 o;
            o.x = fmaxf((float)pmax[i][0].x, (float)pmax[i][0].y)
                + fminf((float)pmin[i][0].x, (float)pmin[i][0].y) + bv.x;
            o.y = fmaxf((float)pmax[i][1].x, (float)pmax[i][1].y)
                + fminf((float)pmin[i][1].x, (float)pmin[i][1].y) + bv.y;
            o.z = fmaxf((float)pmax[i][2].x, (float)pmax[i][2].y)
                + fminf((float)pmin[i][2].x, (float)pmin[i][2].y) + bv.z;
            o.w = fmaxf((float)pmax[i][3].x, (float)pmax[i][3].y)
                + fminf((float)pmin[i][3].x, (float)pmin[i][3].y) + bv.w;
            *(float4*)&out[(size_t)(m0 + m8 + i) * N_DIM + n0 + n4] = o;
        }
    } else {
        unsigned* wp = ws + (size_t)blockIdx.z * NOUT
                          + (size_t)(m0 + m8) * N_DIM + n0 + n4;
#pragma unroll
        for (int i = 0; i < 8; ++i) {
            uint4 v;
            v.x = packmm(pmax[i][0], pmin[i][0]);
            v.y = packmm(pmax[i][1], pmin[i][1]);
            v.z = packmm(pmax[i][2], pmin[i][2]);
            v.w = packmm(pmax[i][3], pmin[i][3]);
            *(uint4*)(wp + (size_t)i * N_DIM) = v;
        }
    }
}

// streaming combine: out = max(4 partial maxes) + min(4 partial mins) + bias
__global__ __launch_bounds__(256) void mam_combine(
    const unsigned* __restrict__ ws, const float* __restrict__ bias,
    float* __restrict__ out)
{
    const int i4 = (blockIdx.x * 256 + threadIdx.x) * 4;
    const uint4 v0 = *(const uint4*)(ws + (size_t)0 * NOUT + i4);
    const uint4 v1 = *(const uint4*)(ws + (size_t)1 * NOUT + i4);
    const uint4 v2 = *(const uint4*)(ws + (size_t)2 * NOUT + i4);
    const uint4 v3 = *(const uint4*)(ws + (size_t)3 * NOUT + i4);
    const float4 bv = *(const float4*)(bias + (i4 % N_DIM));
    float4 o;
#define CMB(e) do {                                                           \
        const h2 a_ = __builtin_bit_cast(h2, v0.e);                           \
        const h2 b_ = __builtin_bit_cast(h2, v1.e);                           \
        const h2 c_ = __builtin_bit_cast(h2, v2.e);                           \
        const h2 d_ = __builtin_bit_cast(h2, v3.e);                           \
        const h2 mx_ = h2max(h2max(a_, b_), h2max(c_, d_));                   \
        const h2 mn_ = h2min(h2min(a_, b_), h2min(c_, d_));                   \
        o.e = (float)mx_.x + (float)mn_.y + bv.e;                             \
    } while (0)
    CMB(x); CMB(y); CMB(z); CMB(w);
#undef CMB
    *(float4*)(out + i4) = o;
}

extern "C" void kernel_launch(void* const* d_in, const int* in_sizes, int n_in,
                              void* d_out, int out_size, void* d_ws, size_t ws_size,
                              hipStream_t stream) {
    const float* x    = (const float*)d_in[0];   // [2,1024,768] -> [2048,768]
    const float* w    = (const float*)d_in[1];   // [768,768] row-major [N][K]
    const float* bias = (const float*)d_in[2];   // [768]
    float* out = (float*)d_out;                  // [2048,768]

    const size_t need = (size_t)4 * NOUT * sizeof(unsigned);   // 25.2 MB
    if (ws_size >= need) {
        // split-K x4: (12,16,4) = 768 blocks = 3 blocks/CU
        mam_main<4><<<dim3(N_DIM / BN, M_DIM / BM, 4), 256, 0, stream>>>(
            x, w, bias, out, (unsigned*)d_ws);
        mam_combine<<<NOUT / 4 / 256, 256, 0, stream>>>(
            (const unsigned*)d_ws, bias, out);
    } else {
        // fallback: full K per block (192 blocks)
        mam_main<1><<<dim3(N_DIM / BN, M_DIM / BM, 1), 256, 0, stream>>>(
            x, w, bias, out, nullptr);
    }
}

// Round 12
// 80.123 us; speedup vs baseline: 5.4260x; 5.4260x over previous
//
#include <hip/hip_runtime.h>
#include <math.h>

// MAM dense: C[i,j] = max_k(A[i,k]*W[j,k]) + min_k(A[i,k]*W[j,k]) + bias[j]
// A = x flat [M=2048, K=768]; W [N=768, K=768] row-major; out [M,N] f32.
// fp16 packed math (pk_mul/pk_max/pk_min = 3 VALU per 2 products = floor).
// R11 lesson: TM8 spills; R10 body (TM4xTN4, VGPR 40) is the proven non-spill
// workhorse. This round: split-K x12 -> each block stages ONE tile, ONE
// __syncthreads, computes, writes packed partials. 4608 blocks, 17KB LDS,
// 8 blocks/CU resident = 8 waves/SIMD; staging overlaps compute via TLP, no
// barrier convoy. Partials (75.5MB) are L3-resident; combine ~5us.

#define M_DIM 2048
#define N_DIM 768
#define K_DIM 768
#define NOUT (M_DIM * N_DIM)   // 1572864

#define BM 64
#define BN 64
#define BK 64
#define KP 32                  // k-pair rows per tile
#define SAH 68                 // A row stride, h2 units (68*4B -> b128 aligned)
#define SBH 68

typedef _Float16 h2 __attribute__((ext_vector_type(2)));   // 4 B
typedef _Float16 h8 __attribute__((ext_vector_type(8)));   // 16 B

static __device__ __forceinline__ h2 cvt_pk(float x, float y) {
    return __builtin_bit_cast(h2, __builtin_amdgcn_cvt_pkrtz(x, y));
}
static __device__ __forceinline__ h2 h2max(h2 a, h2 b) { return __builtin_elementwise_max(a, b); }
static __device__ __forceinline__ h2 h2min(h2 a, h2 b) { return __builtin_elementwise_min(a, b); }
// pack (combined running max, combined running min) into one u32
static __device__ __forceinline__ unsigned packmm(h2 px, h2 pn) {
    h2 r;
    r.x = px.x >= px.y ? px.x : px.y;
    r.y = pn.x <= pn.y ? pn.x : pn.y;
    return __builtin_bit_cast(unsigned, r);
}

template <int NSPL>
__global__ __launch_bounds__(256, 6) void mam_main(
    const float* __restrict__ A, const float* __restrict__ W,
    const float* __restrict__ bias, float* __restrict__ out,
    unsigned* __restrict__ ws)
{
    __shared__ __align__(16) h2 As[KP * SAH];   // 8704 B
    __shared__ __align__(16) h2 Bs[KP * SBH];   // 8704 B (17.4 KB total)

    const int tid = threadIdx.x;
    const int m0  = blockIdx.y * BM;
    const int n0  = blockIdx.x * BN;
    const int NT  = 12 / NSPL;                  // k-tiles this block owns
    const int kb  = blockIdx.z * NT * BK;

    const int mt  = tid >> 4;                   // 0..15 -> rows 4mt..4mt+3
    const int nt  = tid & 15;                   // 0..15 -> cols 4nt..4nt+3
    const int am4 = 4 * mt;
    const int bn4 = 4 * nt;

    h2 pmax[4][4], pmin[4][4];
    const _Float16 HMIN = (_Float16)(-65504.0f), HMAX = (_Float16)(65504.0f);
#pragma unroll
    for (int i = 0; i < 4; ++i)
#pragma unroll
        for (int j = 0; j < 4; ++j) {
            pmax[i][j] = (h2){HMIN, HMIN};
            pmin[i][j] = (h2){HMAX, HMAX};
        }

    // staging: thread -> rows arow+{0,16,32,48}, k-chunk akc (k = akc*4)
    const int arow = tid >> 4;                  // 0..15
    const int akc  = tid & 15;                  // kk2 rows 2akc, 2akc+1
    const int swz  = 4 * (akc & 7);             // XOR col swizzle (bits 2..4)
    const float* Ap = A + (size_t)(m0 + arow) * K_DIM + kb + akc * 4;
    const float* Wp = W + (size_t)(n0 + arow) * K_DIM + kb + akc * 4;

    float4 pa0, pa1, pa2, pa3, pb0, pb1, pb2, pb3;

#define GLOAD(t) do {                                                        \
        const float* An_ = Ap + (t) * BK;                                    \
        const float* Wn_ = Wp + (t) * BK;                                    \
        pa0 = *(const float4*)(An_ + (size_t) 0 * K_DIM);                    \
        pa1 = *(const float4*)(An_ + (size_t)16 * K_DIM);                    \
        pa2 = *(const float4*)(An_ + (size_t)32 * K_DIM);                    \
        pa3 = *(const float4*)(An_ + (size_t)48 * K_DIM);                    \
        pb0 = *(const float4*)(Wn_ + (size_t) 0 * K_DIM);                    \
        pb1 = *(const float4*)(Wn_ + (size_t)16 * K_DIM);                    \
        pb2 = *(const float4*)(Wn_ + (size_t)32 * K_DIM);                    \
        pb3 = *(const float4*)(Wn_ + (size_t)48 * K_DIM);                    \
    } while (0)

#define SWRITE() do {                                                        \
        h2* Aw_ = As + 2 * akc * SAH;                                        \
        h2* Bw_ = Bs + 2 * akc * SBH;                                        \
        const int c0_ = (arow +  0) ^ swz;                                   \
        const int c1_ = (arow + 16) ^ swz;                                   \
        const int c2_ = (arow + 32) ^ swz;                                   \
        const int c3_ = (arow + 48) ^ swz;                                   \
        Aw_[c0_]       = cvt_pk(pa0.x, pa0.y);                               \
        Aw_[SAH + c0_] = cvt_pk(pa0.z, pa0.w);                               \
        Aw_[c1_]       = cvt_pk(pa1.x, pa1.y);                               \
        Aw_[SAH + c1_] = cvt_pk(pa1.z, pa1.w);                               \
        Aw_[c2_]       = cvt_pk(pa2.x, pa2.y);                               \
        Aw_[SAH + c2_] = cvt_pk(pa2.z, pa2.w);                               \
        Aw_[c3_]       = cvt_pk(pa3.x, pa3.y);                               \
        Aw_[SAH + c3_] = cvt_pk(pa3.z, pa3.w);                               \
        Bw_[c0_]       = cvt_pk(pb0.x, pb0.y);                               \
        Bw_[SBH + c0_] = cvt_pk(pb0.z, pb0.w);                               \
        Bw_[c1_]       = cvt_pk(pb1.x, pb1.y);                               \
        Bw_[SBH + c1_] = cvt_pk(pb1.z, pb1.w);                               \
        Bw_[c2_]       = cvt_pk(pb2.x, pb2.y);                               \
        Bw_[SBH + c2_] = cvt_pk(pb2.z, pb2.w);                               \
        Bw_[c3_]       = cvt_pk(pb3.x, pb3.y);                               \
        Bw_[SBH + c3_] = cvt_pk(pb3.z, pb3.w);                               \
    } while (0)

    // reads: data col c sits at LDS col c ^ (4*((kk2>>1)&7)); XOR by mult of
    // 4 preserves b128 contiguity. A: 4 addrs/wave (16-way bcast); B: 16 addrs.
#define COMPUTE() do {                                                       \
        _Pragma("unroll")                                                    \
        for (int kk2 = 0; kk2 < KP; ++kk2) {                                 \
            const int cc_ = 4 * ((kk2 >> 1) & 7);                            \
            const h8 a_ = *(const h8*)(As + kk2 * SAH + (am4 ^ cc_));        \
            const h8 b_ = *(const h8*)(Bs + kk2 * SBH + (bn4 ^ cc_));        \
            const h2 am0 = __builtin_shufflevector(a_, a_, 0, 1);            \
            const h2 am1 = __builtin_shufflevector(a_, a_, 2, 3);            \
            const h2 am2 = __builtin_shufflevector(a_, a_, 4, 5);            \
            const h2 am3 = __builtin_shufflevector(a_, a_, 6, 7);            \
            const h2 bn0 = __builtin_shufflevector(b_, b_, 0, 1);            \
            const h2 bn1 = __builtin_shufflevector(b_, b_, 2, 3);            \
            const h2 bn2 = __builtin_shufflevector(b_, b_, 4, 5);            \
            const h2 bn3 = __builtin_shufflevector(b_, b_, 6, 7);            \
            h2 p_;                                                           \
            p_ = am0 * bn0; pmax[0][0] = h2max(pmax[0][0], p_); pmin[0][0] = h2min(pmin[0][0], p_); \
            p_ = am0 * bn1; pmax[0][1] = h2max(pmax[0][1], p_); pmin[0][1] = h2min(pmin[0][1], p_); \
            p_ = am0 * bn2; pmax[0][2] = h2max(pmax[0][2], p_); pmin[0][2] = h2min(pmin[0][2], p_); \
            p_ = am0 * bn3; pmax[0][3] = h2max(pmax[0][3], p_); pmin[0][3] = h2min(pmin[0][3], p_); \
            p_ = am1 * bn0; pmax[1][0] = h2max(pmax[1][0], p_); pmin[1][0] = h2min(pmin[1][0], p_); \
            p_ = am1 * bn1; pmax[1][1] = h2max(pmax[1][1], p_); pmin[1][1] = h2min(pmin[1][1], p_); \
            p_ = am1 * bn2; pmax[1][2] = h2max(pmax[1][2], p_); pmin[1][2] = h2min(pmin[1][2], p_); \
            p_ = am1 * bn3; pmax[1][3] = h2max(pmax[1][3], p_); pmin[1][3] = h2min(pmin[1][3], p_); \
            p_ = am2 * bn0; pmax[2][0] = h2max(pmax[2][0], p_); pmin[2][0] = h2min(pmin[2][0], p_); \
            p_ = am2 * bn1; pmax[2][1] = h2max(pmax[2][1], p_); pmin[2][1] = h2min(pmin[2][1], p_); \
            p_ = am2 * bn2; pmax[2][2] = h2max(pmax[2][2], p_); pmin[2][2] = h2min(pmin[2][2], p_); \
            p_ = am2 * bn3; pmax[2][3] = h2max(pmax[2][3], p_); pmin[2][3] = h2min(pmin[2][3], p_); \
            p_ = am3 * bn0; pmax[3][0] = h2max(pmax[3][0], p_); pmin[3][0] = h2min(pmin[3][0], p_); \
            p_ = am3 * bn1; pmax[3][1] = h2max(pmax[3][1], p_); pmin[3][1] = h2min(pmin[3][1], p_); \
            p_ = am3 * bn2; pmax[3][2] = h2max(pmax[3][2], p_); pmin[3][2] = h2min(pmin[3][2], p_); \
            p_ = am3 * bn3; pmax[3][3] = h2max(pmax[3][3], p_); pmin[3][3] = h2min(pmin[3][3], p_); \
        }                                                                    \
    } while (0)

    GLOAD(0);
    SWRITE();
    __syncthreads();
#pragma unroll 1
    for (int t = 0; t < NT - 1; ++t) {
        COMPUTE();
        GLOAD(t + 1);
        __syncthreads();
        SWRITE();
        __syncthreads();
    }
    COMPUTE();

    if (NSPL == 1) {
        const float4 bv = *(const float4*)(bias + n0 + bn4);
#pragma unroll
        for (int i = 0; i < 4; ++i) {
            float4 o;
            o.x = fmaxf((float)pmax[i][0].x, (float)pmax[i][0].y)
                + fminf((float)pmin[i][0].x, (float)pmin[i][0].y) + bv.x;
            o.y = fmaxf((float)pmax[i][1].x, (float)pmax[i][1].y)
                + fminf((float)pmin[i][1].x, (float)pmin[i][1].y) + bv.y;
            o.z = fmaxf((float)pmax[i][2].x, (float)pmax[i][2].y)
                + fminf((float)pmin[i][2].x, (float)pmin[i][2].y) + bv.z;
            o.w = fmaxf((float)pmax[i][3].x, (float)pmax[i][3].y)
                + fminf((float)pmin[i][3].x, (float)pmin[i][3].y) + bv.w;
            *(float4*)&out[(size_t)(m0 + am4 + i) * N_DIM + n0 + bn4] = o;
        }
    } else {
        unsigned* wp = ws + (size_t)blockIdx.z * NOUT
                          + (size_t)(m0 + am4) * N_DIM + n0 + bn4;
#pragma unroll
        for (int i = 0; i < 4; ++i) {
            uint4 v;
            v.x = packmm(pmax[i][0], pmin[i][0]);
            v.y = packmm(pmax[i][1], pmin[i][1]);
            v.z = packmm(pmax[i][2], pmin[i][2]);
            v.w = packmm(pmax[i][3], pmin[i][3]);
            *(uint4*)(wp + (size_t)i * N_DIM) = v;
        }
    }
}

// combine: out = max(nspl partial maxes) + min(nspl partial mins) + bias.
// Partials are L3-resident (75.5MB < 256MB).
__global__ __launch_bounds__(256) void mam_combine(
    const unsigned* __restrict__ ws, const float* __restrict__ bias,
    float* __restrict__ out, int nspl)
{
    const int i4 = (blockIdx.x * 256 + threadIdx.x) * 4;
    uint4 v = *(const uint4*)(ws + i4);
    h2 mx0 = __builtin_bit_cast(h2, v.x), mn0 = mx0;
    h2 mx1 = __builtin_bit_cast(h2, v.y), mn1 = mx1;
    h2 mx2 = __builtin_bit_cast(h2, v.z), mn2 = mx2;
    h2 mx3 = __builtin_bit_cast(h2, v.w), mn3 = mx3;
    const unsigned* p = ws + i4;
#pragma unroll 1
    for (int s = 1; s < nspl; ++s) {
        p += NOUT;
        v = *(const uint4*)p;
        h2 t;
        t = __builtin_bit_cast(h2, v.x); mx0 = h2max(mx0, t); mn0 = h2min(mn0, t);
        t = __builtin_bit_cast(h2, v.y); mx1 = h2max(mx1, t); mn1 = h2min(mn1, t);
        t = __builtin_bit_cast(h2, v.z); mx2 = h2max(mx2, t); mn2 = h2min(mn2, t);
        t = __builtin_bit_cast(h2, v.w); mx3 = h2max(mx3, t); mn3 = h2min(mn3, t);
    }
    const float4 bv = *(const float4*)(bias + (i4 % N_DIM));
    float4 o;
    o.x = (float)mx0.x + (float)mn0.y + bv.x;   // .x slot carries max, .y min
    o.y = (float)mx1.x + (float)mn1.y + bv.y;
    o.z = (float)mx2.x + (float)mn2.y + bv.z;
    o.w = (float)mx3.x + (float)mn3.y + bv.w;
    *(float4*)(out + i4) = o;
}

extern "C" void kernel_launch(void* const* d_in, const int* in_sizes, int n_in,
                              void* d_out, int out_size, void* d_ws, size_t ws_size,
                              hipStream_t stream) {
    const float* x    = (const float*)d_in[0];   // [2,1024,768] -> [2048,768]
    const float* w    = (const float*)d_in[1];   // [768,768] row-major [N][K]
    const float* bias = (const float*)d_in[2];   // [768]
    float* out = (float*)d_out;                  // [2048,768]

    const size_t need12 = (size_t)12 * NOUT * sizeof(unsigned);  // 75.5 MB
    const size_t need4  = (size_t)4  * NOUT * sizeof(unsigned);  // 25.2 MB
    if (ws_size >= need12) {
        // split-K x12: one tile per block, one barrier, 4608 blocks
        mam_main<12><<<dim3(N_DIM / BN, M_DIM / BM, 12), 256, 0, stream>>>(
            x, w, bias, out, (unsigned*)d_ws);
        mam_combine<<<NOUT / 4 / 256, 256, 0, stream>>>(
            (const unsigned*)d_ws, bias, out, 12);
    } else if (ws_size >= need4) {
        // proven R10 config
        mam_main<4><<<dim3(N_DIM / BN, M_DIM / BM, 4), 256, 0, stream>>>(
            x, w, bias, out, (unsigned*)d_ws);
        mam_combine<<<NOUT / 4 / 256, 256, 0, stream>>>(
            (const unsigned*)d_ws, bias, out, 4);
    } else {
        mam_main<1><<<dim3(N_DIM / BN, M_DIM / BM, 1), 256, 0, stream>>>(
            x, w, bias, out, nullptr);
    }
}

// Round 13
// 79.268 us; speedup vs baseline: 5.4845x; 1.0108x over previous
//
#include <hip/hip_runtime.h>
#include <math.h>

// MAM dense: C[i,j] = max_k(A[i,k]*W[j,k]) + min_k(A[i,k]*W[j,k]) + bias[j]
// A = x flat [M=2048, K=768]; W [N=768, K=768] row-major; out [M,N] f32.
// R12 structure (split-K x12, one tile/block, one barrier, packed partials)
// with the inner loop PINNED: inline-asm v_pk_mul_f16/v_pk_max_f16/v_pk_min_f16
// (exactly 48 VALU per kk2 -- decisive test of the "clang scalarizes h2
// max/min" hypothesis) + explicit 1-deep kk2 prefetch with named h8 regs.

#define M_DIM 2048
#define N_DIM 768
#define K_DIM 768
#define NOUT (M_DIM * N_DIM)   // 1572864

#define BM 64
#define BN 64
#define BK 64
#define KP 32                  // k-pair rows per tile
#define SAH 68                 // A row stride, h2 units (68*4B -> b128 aligned)
#define SBH 68

typedef _Float16 h2 __attribute__((ext_vector_type(2)));   // 4 B
typedef _Float16 h8 __attribute__((ext_vector_type(8)));   // 16 B

static __device__ __forceinline__ h2 cvt_pk(float x, float y) {
    return __builtin_bit_cast(h2, __builtin_amdgcn_cvt_pkrtz(x, y));
}
// forced single-instruction packed f16 ops (bitcast through u32; VOP3P)
static __device__ __forceinline__ h2 h2mul(h2 a, h2 b) {
    unsigned d;
    asm("v_pk_mul_f16 %0, %1, %2" : "=v"(d)
        : "v"(__builtin_bit_cast(unsigned, a)), "v"(__builtin_bit_cast(unsigned, b)));
    return __builtin_bit_cast(h2, d);
}
static __device__ __forceinline__ h2 h2max(h2 a, h2 b) {
    unsigned d;
    asm("v_pk_max_f16 %0, %1, %2" : "=v"(d)
        : "v"(__builtin_bit_cast(unsigned, a)), "v"(__builtin_bit_cast(unsigned, b)));
    return __builtin_bit_cast(h2, d);
}
static __device__ __forceinline__ h2 h2min(h2 a, h2 b) {
    unsigned d;
    asm("v_pk_min_f16 %0, %1, %2" : "=v"(d)
        : "v"(__builtin_bit_cast(unsigned, a)), "v"(__builtin_bit_cast(unsigned, b)));
    return __builtin_bit_cast(h2, d);
}
// pack (combined running max, combined running min) into one u32
static __device__ __forceinline__ unsigned packmm(h2 px, h2 pn) {
    h2 r;
    r.x = px.x >= px.y ? px.x : px.y;
    r.y = pn.x <= pn.y ? pn.x : pn.y;
    return __builtin_bit_cast(unsigned, r);
}

// LDS reads; k2 compile-time under full unroll. Data col c lives at LDS col
// c ^ (4*((k2>>1)&7)); XOR by mult of 4 preserves b128 contiguity.
#define SWZC(k2) (4 * (((k2) >> 1) & 7))
#define LDA(k2) (*(const h8*)(As + (k2) * SAH + (am4 ^ SWZC(k2))))
#define LDB(k2) (*(const h8*)(Bs + (k2) * SBH + (bn4 ^ SWZC(k2))))

// 48 forced pk ops on one kk2 slice
#define MAMOPS(A_, B_) do {                                                  \
        const h2 am0 = __builtin_shufflevector(A_, A_, 0, 1);                \
        const h2 am1 = __builtin_shufflevector(A_, A_, 2, 3);                \
        const h2 am2 = __builtin_shufflevector(A_, A_, 4, 5);                \
        const h2 am3 = __builtin_shufflevector(A_, A_, 6, 7);                \
        const h2 bn0 = __builtin_shufflevector(B_, B_, 0, 1);                \
        const h2 bn1 = __builtin_shufflevector(B_, B_, 2, 3);                \
        const h2 bn2 = __builtin_shufflevector(B_, B_, 4, 5);                \
        const h2 bn3 = __builtin_shufflevector(B_, B_, 6, 7);                \
        h2 p_;                                                               \
        p_ = h2mul(am0, bn0); pmax[0][0] = h2max(pmax[0][0], p_); pmin[0][0] = h2min(pmin[0][0], p_); \
        p_ = h2mul(am0, bn1); pmax[0][1] = h2max(pmax[0][1], p_); pmin[0][1] = h2min(pmin[0][1], p_); \
        p_ = h2mul(am0, bn2); pmax[0][2] = h2max(pmax[0][2], p_); pmin[0][2] = h2min(pmin[0][2], p_); \
        p_ = h2mul(am0, bn3); pmax[0][3] = h2max(pmax[0][3], p_); pmin[0][3] = h2min(pmin[0][3], p_); \
        p_ = h2mul(am1, bn0); pmax[1][0] = h2max(pmax[1][0], p_); pmin[1][0] = h2min(pmin[1][0], p_); \
        p_ = h2mul(am1, bn1); pmax[1][1] = h2max(pmax[1][1], p_); pmin[1][1] = h2min(pmin[1][1], p_); \
        p_ = h2mul(am1, bn2); pmax[1][2] = h2max(pmax[1][2], p_); pmin[1][2] = h2min(pmin[1][2], p_); \
        p_ = h2mul(am1, bn3); pmax[1][3] = h2max(pmax[1][3], p_); pmin[1][3] = h2min(pmin[1][3], p_); \
        p_ = h2mul(am2, bn0); pmax[2][0] = h2max(pmax[2][0], p_); pmin[2][0] = h2min(pmin[2][0], p_); \
        p_ = h2mul(am2, bn1); pmax[2][1] = h2max(pmax[2][1], p_); pmin[2][1] = h2min(pmin[2][1], p_); \
        p_ = h2mul(am2, bn2); pmax[2][2] = h2max(pmax[2][2], p_); pmin[2][2] = h2min(pmin[2][2], p_); \
        p_ = h2mul(am2, bn3); pmax[2][3] = h2max(pmax[2][3], p_); pmin[2][3] = h2min(pmin[2][3], p_); \
        p_ = h2mul(am3, bn0); pmax[3][0] = h2max(pmax[3][0], p_); pmin[3][0] = h2min(pmin[3][0], p_); \
        p_ = h2mul(am3, bn1); pmax[3][1] = h2max(pmax[3][1], p_); pmin[3][1] = h2min(pmin[3][1], p_); \
        p_ = h2mul(am3, bn2); pmax[3][2] = h2max(pmax[3][2], p_); pmin[3][2] = h2min(pmin[3][2], p_); \
        p_ = h2mul(am3, bn3); pmax[3][3] = h2max(pmax[3][3], p_); pmin[3][3] = h2min(pmin[3][3], p_); \
    } while (0)

template <int NSPL>
__global__ __launch_bounds__(256, 6) void mam_main(
    const float* __restrict__ A, const float* __restrict__ W,
    const float* __restrict__ bias, float* __restrict__ out,
    unsigned* __restrict__ ws)
{
    __shared__ __align__(16) h2 As[KP * SAH];   // 8704 B
    __shared__ __align__(16) h2 Bs[KP * SBH];   // 8704 B (17.4 KB total)

    const int tid = threadIdx.x;
    const int m0  = blockIdx.y * BM;
    const int n0  = blockIdx.x * BN;
    const int NT  = 12 / NSPL;                  // k-tiles this block owns
    const int kb  = blockIdx.z * NT * BK;

    const int mt  = tid >> 4;                   // 0..15 -> rows 4mt..4mt+3
    const int nt  = tid & 15;                   // 0..15 -> cols 4nt..4nt+3
    const int am4 = 4 * mt;
    const int bn4 = 4 * nt;

    h2 pmax[4][4], pmin[4][4];
    const _Float16 HMIN = (_Float16)(-65504.0f), HMAX = (_Float16)(65504.0f);
#pragma unroll
    for (int i = 0; i < 4; ++i)
#pragma unroll
        for (int j = 0; j < 4; ++j) {
            pmax[i][j] = (h2){HMIN, HMIN};
            pmin[i][j] = (h2){HMAX, HMAX};
        }

    // staging: thread -> rows arow+{0,16,32,48}, k-chunk akc (k = akc*4)
    const int arow = tid >> 4;                  // 0..15
    const int akc  = tid & 15;                  // kk2 rows 2akc, 2akc+1
    const int swz  = 4 * (akc & 7);             // XOR col swizzle (bits 2..4)
    const float* Ap = A + (size_t)(m0 + arow) * K_DIM + kb + akc * 4;
    const float* Wp = W + (size_t)(n0 + arow) * K_DIM + kb + akc * 4;

    float4 pa0, pa1, pa2, pa3, pb0, pb1, pb2, pb3;

#define GLOAD(t) do {                                                        \
        const float* An_ = Ap + (t) * BK;                                    \
        const float* Wn_ = Wp + (t) * BK;                                    \
        pa0 = *(const float4*)(An_ + (size_t) 0 * K_DIM);                    \
        pa1 = *(const float4*)(An_ + (size_t)16 * K_DIM);                    \
        pa2 = *(const float4*)(An_ + (size_t)32 * K_DIM);                    \
        pa3 = *(const float4*)(An_ + (size_t)48 * K_DIM);                    \
        pb0 = *(const float4*)(Wn_ + (size_t) 0 * K_DIM);                    \
        pb1 = *(const float4*)(Wn_ + (size_t)16 * K_DIM);                    \
        pb2 = *(const float4*)(Wn_ + (size_t)32 * K_DIM);                    \
        pb3 = *(const float4*)(Wn_ + (size_t)48 * K_DIM);                    \
    } while (0)

#define SWRITE() do {                                                        \
        h2* Aw_ = As + 2 * akc * SAH;                                        \
        h2* Bw_ = Bs + 2 * akc * SBH;                                        \
        const int c0_ = (arow +  0) ^ swz;                                   \
        const int c1_ = (arow + 16) ^ swz;                                   \
        const int c2_ = (arow + 32) ^ swz;                                   \
        const int c3_ = (arow + 48) ^ swz;                                   \
        Aw_[c0_]       = cvt_pk(pa0.x, pa0.y);                               \
        Aw_[SAH + c0_] = cvt_pk(pa0.z, pa0.w);                               \
        Aw_[c1_]       = cvt_pk(pa1.x, pa1.y);                               \
        Aw_[SAH + c1_] = cvt_pk(pa1.z, pa1.w);                               \
        Aw_[c2_]       = cvt_pk(pa2.x, pa2.y);                               \
        Aw_[SAH + c2_] = cvt_pk(pa2.z, pa2.w);                               \
        Aw_[c3_]       = cvt_pk(pa3.x, pa3.y);                               \
        Aw_[SAH + c3_] = cvt_pk(pa3.z, pa3.w);                               \
        Bw_[c0_]       = cvt_pk(pb0.x, pb0.y);                               \
        Bw_[SBH + c0_] = cvt_pk(pb0.z, pb0.w);                               \
        Bw_[c1_]       = cvt_pk(pb1.x, pb1.y);                               \
        Bw_[SBH + c1_] = cvt_pk(pb1.z, pb1.w);                               \
        Bw_[c2_]       = cvt_pk(pb2.x, pb2.y);                               \
        Bw_[SBH + c2_] = cvt_pk(pb2.z, pb2.w);                               \
        Bw_[c3_]       = cvt_pk(pb3.x, pb3.y);                               \
        Bw_[SBH + c3_] = cvt_pk(pb3.z, pb3.w);                               \
    } while (0)

    // compute with explicit 1-deep kk2 prefetch (named h8 regs, const offsets)
#define COMPUTE() do {                                                       \
        h8 cA_ = LDA(0), cB_ = LDB(0);                                       \
        _Pragma("unroll")                                                    \
        for (int kk2 = 0; kk2 < KP - 1; ++kk2) {                             \
            const h8 nA_ = LDA(kk2 + 1);                                     \
            const h8 nB_ = LDB(kk2 + 1);                                     \
            MAMOPS(cA_, cB_);                                                \
            cA_ = nA_; cB_ = nB_;                                            \
        }                                                                    \
        MAMOPS(cA_, cB_);                                                    \
    } while (0)

    GLOAD(0);
    SWRITE();
    __syncthreads();
#pragma unroll 1
    for (int t = 0; t < NT - 1; ++t) {
        COMPUTE();
        GLOAD(t + 1);
        __syncthreads();
        SWRITE();
        __syncthreads();
    }
    COMPUTE();

    if (NSPL == 1) {
        const float4 bv = *(const float4*)(bias + n0 + bn4);
#pragma unroll
        for (int i = 0; i < 4; ++i) {
            float4 o;
            o.x = fmaxf((float)pmax[i][0].x, (float)pmax[i][0].y)
                + fminf((float)pmin[i][0].x, (float)pmin[i][0].y) + bv.x;
            o.y = fmaxf((float)pmax[i][1].x, (float)pmax[i][1].y)
                + fminf((float)pmin[i][1].x, (float)pmin[i][1].y) + bv.y;
            o.z = fmaxf((float)pmax[i][2].x, (float)pmax[i][2].y)
                + fminf((float)pmin[i][2].x, (float)pmin[i][2].y) + bv.z;
            o.w = fmaxf((float)pmax[i][3].x, (float)pmax[i][3].y)
                + fminf((float)pmin[i][3].x, (float)pmin[i][3].y) + bv.w;
            *(float4*)&out[(size_t)(m0 + am4 + i) * N_DIM + n0 + bn4] = o;
        }
    } else {
        unsigned* wp = ws + (size_t)blockIdx.z * NOUT
                          + (size_t)(m0 + am4) * N_DIM + n0 + bn4;
#pragma unroll
        for (int i = 0; i < 4; ++i) {
            uint4 v;
            v.x = packmm(pmax[i][0], pmin[i][0]);
            v.y = packmm(pmax[i][1], pmin[i][1]);
            v.z = packmm(pmax[i][2], pmin[i][2]);
            v.w = packmm(pmax[i][3], pmin[i][3]);
            *(uint4*)(wp + (size_t)i * N_DIM) = v;
        }
    }
}

// combine: out = max(nspl partial maxes) + min(nspl partial mins) + bias.
__global__ __launch_bounds__(256) void mam_combine(
    const unsigned* __restrict__ ws, const float* __restrict__ bias,
    float* __restrict__ out, int nspl)
{
    const int i4 = (blockIdx.x * 256 + threadIdx.x) * 4;
    uint4 v = *(const uint4*)(ws + i4);
    h2 mx0 = __builtin_bit_cast(h2, v.x), mn0 = mx0;
    h2 mx1 = __builtin_bit_cast(h2, v.y), mn1 = mx1;
    h2 mx2 = __builtin_bit_cast(h2, v.z), mn2 = mx2;
    h2 mx3 = __builtin_bit_cast(h2, v.w), mn3 = mx3;
    const unsigned* p = ws + i4;
#pragma unroll 1
    for (int s = 1; s < nspl; ++s) {
        p += NOUT;
        v = *(const uint4*)p;
        h2 t;
        t = __builtin_bit_cast(h2, v.x); mx0 = h2max(mx0, t); mn0 = h2min(mn0, t);
        t = __builtin_bit_cast(h2, v.y); mx1 = h2max(mx1, t); mn1 = h2min(mn1, t);
        t = __builtin_bit_cast(h2, v.z); mx2 = h2max(mx2, t); mn2 = h2min(mn2, t);
        t = __builtin_bit_cast(h2, v.w); mx3 = h2max(mx3, t); mn3 = h2min(mn3, t);
    }
    const float4 bv = *(const float4*)(bias + (i4 % N_DIM));
    float4 o;
    o.x = (float)mx0.x + (float)mn0.y + bv.x;   // .x slot carries max, .y min
    o.y = (float)mx1.x + (float)mn1.y + bv.y;
    o.z = (float)mx2.x + (float)mn2.y + bv.z;
    o.w = (float)mx3.x + (float)mn3.y + bv.w;
    *(float4*)(out + i4) = o;
}

extern "C" void kernel_launch(void* const* d_in, const int* in_sizes, int n_in,
                              void* d_out, int out_size, void* d_ws, size_t ws_size,
                              hipStream_t stream) {
    const float* x    = (const float*)d_in[0];   // [2,1024,768] -> [2048,768]
    const float* w    = (const float*)d_in[1];   // [768,768] row-major [N][K]
    const float* bias = (const float*)d_in[2];   // [768]
    float* out = (float*)d_out;                  // [2048,768]

    const size_t need12 = (size_t)12 * NOUT * sizeof(unsigned);  // 75.5 MB
    const size_t need4  = (size_t)4  * NOUT * sizeof(unsigned);  // 25.2 MB
    if (ws_size >= need12) {
        mam_main<12><<<dim3(N_DIM / BN, M_DIM / BM, 12), 256, 0, stream>>>(
            x, w, bias, out, (unsigned*)d_ws);
        mam_combine<<<NOUT / 4 / 256, 256, 0, stream>>>(
            (const unsigned*)d_ws, bias, out, 12);
    } else if (ws_size >= need4) {
        mam_main<4><<<dim3(N_DIM / BN, M_DIM / BM, 4), 256, 0, stream>>>(
            x, w, bias, out, (unsigned*)d_ws);
        mam_combine<<<NOUT / 4 / 256, 256, 0, stream>>>(
            (const unsigned*)d_ws, bias, out, 4);
    } else {
        mam_main<1><<<dim3(N_DIM / BN, M_DIM / BM, 1), 256, 0, stream>>>(
            x, w, bias, out, nullptr);
    }
}

// Round 14
// 62.731 us; speedup vs baseline: 6.9303x; 1.2636x over previous
//
#include <hip/hip_runtime.h>
#include <math.h>

// MAM dense: C[i,j] = max_k(A[i,k]*W[j,k]) + min_k(A[i,k]*W[j,k]) + bias[j]
// A = x flat [M=2048, K=768]; W [N=768, K=768] row-major; out [M,N] f32.
// Single kernel (split-K combine costs ~10us > its gain). R8 base: BM64xBN32,
// TM4xTN2, 768 blocks = 3/CU, double-buffered LDS, one barrier per tile.
// This round isolates the LAST unknown: per-trio dependency stalls. Inner loop
// batched as 8 independent pk_muls -> 8 pk_max -> 8 pk_min (forced asm), with
// 1-deep kk2 LDS prefetch. If this doesn't move, ~69us is the empirical
// VALU-rate ceiling (~4.3 cyc/wave64-VALU measured across 5 structures).

#define M_DIM 2048
#define N_DIM 768
#define K_DIM 768

#define BM 64
#define BN 32
#define BK 64
#define KP (BK / 2)            // 32 k-pair rows per tile
#define NTILES (K_DIM / BK)    // 12

// LDS strides in h2 (4B) units (R8-proven layout).
#define SAH 68                 // A: b128 read 16B-aligned, 16-way broadcast
#define SBH 34                 // B: b64 read, banks spread

typedef _Float16 h2 __attribute__((ext_vector_type(2)));   // 4 B
typedef _Float16 h4 __attribute__((ext_vector_type(4)));   // 8 B
typedef _Float16 h8 __attribute__((ext_vector_type(8)));   // 16 B

static __device__ __forceinline__ h2 cvt_pk(float x, float y) {
    return __builtin_bit_cast(h2, __builtin_amdgcn_cvt_pkrtz(x, y));
}
// forced single-instruction packed f16 ops
static __device__ __forceinline__ h2 h2mul(h2 a, h2 b) {
    unsigned d;
    asm("v_pk_mul_f16 %0, %1, %2" : "=v"(d)
        : "v"(__builtin_bit_cast(unsigned, a)), "v"(__builtin_bit_cast(unsigned, b)));
    return __builtin_bit_cast(h2, d);
}
static __device__ __forceinline__ h2 h2max(h2 a, h2 b) {
    unsigned d;
    asm("v_pk_max_f16 %0, %1, %2" : "=v"(d)
        : "v"(__builtin_bit_cast(unsigned, a)), "v"(__builtin_bit_cast(unsigned, b)));
    return __builtin_bit_cast(h2, d);
}
static __device__ __forceinline__ h2 h2min(h2 a, h2 b) {
    unsigned d;
    asm("v_pk_min_f16 %0, %1, %2" : "=v"(d)
        : "v"(__builtin_bit_cast(unsigned, a)), "v"(__builtin_bit_cast(unsigned, b)));
    return __builtin_bit_cast(h2, d);
}

// batched inner slice: 8 independent muls, then 8 maxes, then 8 mins.
#define MAMOPS(A_, B_) do {                                                  \
        const h2 am0 = __builtin_shufflevector(A_, A_, 0, 1);                \
        const h2 am1 = __builtin_shufflevector(A_, A_, 2, 3);                \
        const h2 am2 = __builtin_shufflevector(A_, A_, 4, 5);                \
        const h2 am3 = __builtin_shufflevector(A_, A_, 6, 7);                \
        const h2 bn0 = __builtin_shufflevector(B_, B_, 0, 1);                \
        const h2 bn1 = __builtin_shufflevector(B_, B_, 2, 3);                \
        const h2 q0 = h2mul(am0, bn0);                                       \
        const h2 q1 = h2mul(am1, bn0);                                       \
        const h2 q2 = h2mul(am2, bn0);                                       \
        const h2 q3 = h2mul(am3, bn0);                                       \
        const h2 q4 = h2mul(am0, bn1);                                       \
        const h2 q5 = h2mul(am1, bn1);                                       \
        const h2 q6 = h2mul(am2, bn1);                                       \
        const h2 q7 = h2mul(am3, bn1);                                       \
        pmax[0][0] = h2max(pmax[0][0], q0);                                  \
        pmax[1][0] = h2max(pmax[1][0], q1);                                  \
        pmax[2][0] = h2max(pmax[2][0], q2);                                  \
        pmax[3][0] = h2max(pmax[3][0], q3);                                  \
        pmax[0][1] = h2max(pmax[0][1], q4);                                  \
        pmax[1][1] = h2max(pmax[1][1], q5);                                  \
        pmax[2][1] = h2max(pmax[2][1], q6);                                  \
        pmax[3][1] = h2max(pmax[3][1], q7);                                  \
        pmin[0][0] = h2min(pmin[0][0], q0);                                  \
        pmin[1][0] = h2min(pmin[1][0], q1);                                  \
        pmin[2][0] = h2min(pmin[2][0], q2);                                  \
        pmin[3][0] = h2min(pmin[3][0], q3);                                  \
        pmin[0][1] = h2min(pmin[0][1], q4);                                  \
        pmin[1][1] = h2min(pmin[1][1], q5);                                  \
        pmin[2][1] = h2min(pmin[2][1], q6);                                  \
        pmin[3][1] = h2min(pmin[3][1], q7);                                  \
    } while (0)

__global__ __launch_bounds__(256, 3) void mam_kernel(
    const float* __restrict__ A, const float* __restrict__ W,
    const float* __restrict__ bias, float* __restrict__ out)
{
    __shared__ __align__(16) h2 As[2][KP * SAH];
    __shared__ __align__(16) h2 Bs[2][KP * SBH];

    const int tid = threadIdx.x;
    const int m0 = blockIdx.y * BM;
    const int n0 = blockIdx.x * BN;
    const int mt = tid >> 4;   // 0..15 -> rows mt*4..mt*4+3
    const int nt = tid & 15;   // 0..15 -> cols nt*2..nt*2+1

    h2 pmax[4][2], pmin[4][2];
    const _Float16 HMIN = (_Float16)(-65504.0f), HMAX = (_Float16)(65504.0f);
#pragma unroll
    for (int i = 0; i < 4; ++i)
#pragma unroll
        for (int j = 0; j < 2; ++j) {
            pmax[i][j] = (h2){HMIN, HMIN};
            pmin[i][j] = (h2){HMAX, HMAX};
        }

    // staging map (R8): thread -> rows arow+16q, k-chunk akc (kk2 = 2akc,+1)
    const int arow = tid >> 4;
    const int akc  = tid & 15;
    const float* Ap = A + (size_t)(m0 + arow) * K_DIM + akc * 4;
    const float* Wp = W + (size_t)(n0 + arow) * K_DIM + akc * 4;

    const float bb0 = bias[n0 + nt * 2 + 0];
    const float bb1 = bias[n0 + nt * 2 + 1];

    float4 pa0, pa1, pa2, pa3, pb0, pb1;

#define GLOAD(t) do {                                                        \
        const float* An_ = Ap + (t) * BK;                                    \
        const float* Wn_ = Wp + (t) * BK;                                    \
        pa0 = *(const float4*)(An_ + (size_t) 0 * K_DIM);                    \
        pa1 = *(const float4*)(An_ + (size_t)16 * K_DIM);                    \
        pa2 = *(const float4*)(An_ + (size_t)32 * K_DIM);                    \
        pa3 = *(const float4*)(An_ + (size_t)48 * K_DIM);                    \
        pb0 = *(const float4*)(Wn_ + (size_t) 0 * K_DIM);                    \
        pb1 = *(const float4*)(Wn_ + (size_t)16 * K_DIM);                    \
    } while (0)

#define SWRITE(buf) do {                                                     \
        h2* Aw_ = &As[buf][2 * akc * SAH + arow];                            \
        Aw_[0]        = cvt_pk(pa0.x, pa0.y);                                \
        Aw_[SAH]      = cvt_pk(pa0.z, pa0.w);                                \
        Aw_[16]       = cvt_pk(pa1.x, pa1.y);                                \
        Aw_[SAH + 16] = cvt_pk(pa1.z, pa1.w);                                \
        Aw_[32]       = cvt_pk(pa2.x, pa2.y);                                \
        Aw_[SAH + 32] = cvt_pk(pa2.z, pa2.w);                                \
        Aw_[48]       = cvt_pk(pa3.x, pa3.y);                                \
        Aw_[SAH + 48] = cvt_pk(pa3.z, pa3.w);                                \
        h2* Bw_ = &Bs[buf][2 * akc * SBH + arow];                            \
        Bw_[0]        = cvt_pk(pb0.x, pb0.y);                                \
        Bw_[SBH]      = cvt_pk(pb0.z, pb0.w);                                \
        Bw_[16]       = cvt_pk(pb1.x, pb1.y);                                \
        Bw_[SBH + 16] = cvt_pk(pb1.z, pb1.w);                                \
    } while (0)

    // compute with explicit 1-deep kk2 prefetch (named regs, const offsets)
#define COMPUTE(buf) do {                                                    \
        const h2* Ab_ = &As[buf][mt * 4];                                    \
        const h2* Bb_ = &Bs[buf][nt * 2];                                    \
        h8 cA_ = *(const h8*)(Ab_);                                          \
        h4 cB_ = *(const h4*)(Bb_);                                          \
        _Pragma("unroll")                                                    \
        for (int kk2 = 0; kk2 < KP - 1; ++kk2) {                             \
            const h8 nA_ = *(const h8*)(Ab_ + (kk2 + 1) * SAH);              \
            const h4 nB_ = *(const h4*)(Bb_ + (kk2 + 1) * SBH);              \
            MAMOPS(cA_, cB_);                                                \
            cA_ = nA_; cB_ = nB_;                                            \
        }                                                                    \
        MAMOPS(cA_, cB_);                                                    \
    } while (0)

    // prologue: tile 0 -> buf 0
    GLOAD(0);
    SWRITE(0);
    __syncthreads();

    // main loop: double-buffered, one barrier per tile
#pragma unroll 1
    for (int ktt = 0; ktt < NTILES / 2 - 1; ++ktt) {
        GLOAD(2 * ktt + 1);        // issue early: latency hides under compute
        COMPUTE(0);
        SWRITE(1);                 // write late: loads have landed
        __syncthreads();
        GLOAD(2 * ktt + 2);
        COMPUTE(1);
        SWRITE(0);
        __syncthreads();
    }
    // peeled tail: tile 10 (buf0) while staging tile 11, then tile 11 (buf1)
    GLOAD(NTILES - 1);
    COMPUTE(0);
    SWRITE(1);
    __syncthreads();
    COMPUTE(1);

    // epilogue: combine even/odd extrema, add bias, store f32
#pragma unroll
    for (int i = 0; i < 4; ++i) {
        float2 o;
        o.x = fmaxf((float)pmax[i][0].x, (float)pmax[i][0].y)
            + fminf((float)pmin[i][0].x, (float)pmin[i][0].y) + bb0;
        o.y = fmaxf((float)pmax[i][1].x, (float)pmax[i][1].y)
            + fminf((float)pmin[i][1].x, (float)pmin[i][1].y) + bb1;
        *(float2*)&out[(size_t)(m0 + mt * 4 + i) * N_DIM + n0 + nt * 2] = o;
    }
}

extern "C" void kernel_launch(void* const* d_in, const int* in_sizes, int n_in,
                              void* d_out, int out_size, void* d_ws, size_t ws_size,
                              hipStream_t stream) {
    const float* x    = (const float*)d_in[0];   // [2,1024,768] -> [2048,768]
    const float* w    = (const float*)d_in[1];   // [768,768] row-major [N][K]
    const float* bias = (const float*)d_in[2];   // [768]
    float* out = (float*)d_out;                  // [2048,768]

    dim3 grid(N_DIM / BN, M_DIM / BM);           // (24, 32) = 768 blocks = 3/CU
    mam_kernel<<<grid, 256, 0, stream>>>(x, w, bias, out);
}